// Round 11
// baseline (242.739 us; speedup 1.0000x reference)
//
#include <hip/hip_runtime.h>
#include <cstdint>
#include <cstddef>

// ---------------------------------------------------------------------------
// APPNPNet_Structural: FC1-first (prop commutes with right-mul) -> APPNP K=3
// in 64-dim bf16 pre-scaled space -> fused head (softmax pool + MLP).
// Round 11: pull back to 8-edge step / 4-edge tail (12% pad waste vs 45%);
// fc1 emits g0=dinv*y directly; single fused head kernel (online softmax,
// no intermediate buffers). 16 -> 9 dispatches.
// ---------------------------------------------------------------------------

#define DIN 128
#define NEU 64
#define BK2 512            // nodes per bucket
#define BKSHIFT2 9
#define BKCAP 16384        // per-bucket global staging capacity (mean 8192)
#define ESCAP 12288        // per-bucket LDS sort capacity (48KB)
#define MAXNB 256

typedef __attribute__((ext_vector_type(8))) short short8v;   // 8 bf16 (4 VGPRs)
typedef __attribute__((ext_vector_type(4))) float f32x4;     // 4 fp32 acc

// bf16 helpers: storage = ushort, math = f32.
__device__ inline float bf2f(unsigned short h) {
    return __uint_as_float(((unsigned)h) << 16);
}
__device__ inline unsigned short f2bf(float f) {   // round-to-nearest-even
    unsigned u = __float_as_uint(f);
    unsigned r = u + 0x7FFFu + ((u >> 16) & 1u);
    return (unsigned short)(r >> 16);
}

// ---------------- Phase A: coarse binning, packed 4B payload ----------------

__global__ __launch_bounds__(256) void binA_kernel(
        const int* __restrict__ src, const int* __restrict__ dst,
        int* __restrict__ bcur, int* __restrict__ pk, int E, int NB) {
    __shared__ int hist[MAXNB];
    __shared__ int cur[MAXNB];
    int nchunk = gridDim.x;
    int chunk = (E + nchunk - 1) / nchunk;
    int lo = blockIdx.x * chunk;
    int hi = min(E, lo + chunk);
    int t = threadIdx.x;
    for (int b = t; b < NB; b += 256) hist[b] = 0;
    __syncthreads();
    for (int i = lo + t; i < hi; i += 256)
        atomicAdd(&hist[dst[i] >> BKSHIFT2], 1);
    __syncthreads();
    for (int b = t; b < NB; b += 256)
        cur[b] = atomicAdd(&bcur[b], hist[b]);
    __syncthreads();
    for (int i = lo + t; i < hi; i += 256) {
        int d = dst[i];
        int b = d >> BKSHIFT2;
        int pos = atomicAdd(&cur[b], 1);
        pk[(size_t)b * BKCAP + pos] = (src[i] << BKSHIFT2) | (d & (BK2 - 1));
    }
}

// ---------------- exclusive scan of bucket counts ----------------

__global__ void bscan_kernel(const int* __restrict__ bcur, int* __restrict__ bbase, int NB) {
    __shared__ int sh[256];
    int t = threadIdx.x;
    sh[t] = (t < NB) ? bcur[t] : 0;
    __syncthreads();
    for (int d = 1; d < 256; d <<= 1) {
        int v = (t >= d) ? sh[t - d] : 0;
        __syncthreads();
        sh[t] += v;
        __syncthreads();
    }
    if (t < NB) bbase[t + 1] = sh[t];
    if (t == 0) bbase[0] = 0;
}

// ---------------- Phase B: per-bucket LDS counting sort ----------------

__global__ __launch_bounds__(256) void binB_kernel(
        const int* __restrict__ bcur, const int* __restrict__ bbase,
        const int* __restrict__ pk, int* __restrict__ es,
        int* __restrict__ rowptr, float* __restrict__ dinv, int N, int NB) {
    __shared__ int cur[BK2];      // 2 KB: counts -> cursors
    __shared__ int sh[256];       // 1 KB: scan workspace
    __shared__ int esl[ESCAP];    // 48 KB: sorted srcs
    int b = blockIdx.x;
    int t = threadIdx.x;
    int node0 = b << BKSHIFT2;
    int count = bcur[b];
    int base = bbase[b];
    const int* pb = pk + (size_t)b * BKCAP;

    for (int v = t; v < BK2; v += 256) cur[v] = 0;
    __syncthreads();
    for (int i = t; i < count; i += 256)
        atomicAdd(&cur[pb[i] & (BK2 - 1)], 1);
    __syncthreads();
    int c0 = cur[2 * t], c1 = cur[2 * t + 1];
    int s = c0 + c1;
    sh[t] = s;
    __syncthreads();
    for (int d = 1; d < 256; d <<= 1) {
        int v = (t >= d) ? sh[t - d] : 0;
        __syncthreads();
        sh[t] += v;
        __syncthreads();
    }
    int excl = sh[t] - s;
    int n0 = node0 + 2 * t;
    if (n0 < N) {
        rowptr[n0 + 1] = base + excl + c0;
        dinv[n0] = rsqrtf((float)c0 + 1.0f);
    }
    if (n0 + 1 < N) {
        rowptr[n0 + 2] = base + excl + c0 + c1;
        dinv[n0 + 1] = rsqrtf((float)c1 + 1.0f);
    }
    if (b == 0 && t == 0) rowptr[0] = 0;
    __syncthreads();
    cur[2 * t] = excl;
    cur[2 * t + 1] = excl + c0;
    __syncthreads();
    for (int i = t; i < count; i += 256) {
        int v = pb[i];
        int pos = atomicAdd(&cur[v & (BK2 - 1)], 1);
        if (pos < ESCAP) esl[pos] = v >> BKSHIFT2;
    }
    __syncthreads();
    for (int i = t; i < count; i += 256) es[base + i] = esl[i];
}

// ---------------- FC1 via MFMA: y = x @ W1, g0 = dinv*y (bf16) ----------------

__global__ __launch_bounds__(256) void fc1_kernel(
        const float* __restrict__ x, const float* __restrict__ W,
        const float* __restrict__ dinv, ushort* __restrict__ yb,
        ushort* __restrict__ g0, ushort* __restrict__ g1,
        ushort* __restrict__ g2, int N) {
    int tid = threadIdx.x;
    // zero pad-row N of all three g buffers (block 0 never early-returns)
    if (blockIdx.x == 0 && tid < 48) {
        int buf = tid >> 4, e = tid & 15;
        ushort* gp = (buf == 0) ? g0 : (buf == 1) ? g1 : g2;
        ((ushort4*)(gp + (size_t)N * NEU))[e] = make_ushort4(0, 0, 0, 0);
    }
    __shared__ ushort sW[DIN * NEU];   // bf16 W, 16 KB
    for (int k = tid; k < DIN * NEU / 2; k += 256) {
        float2 v = ((const float2*)W)[k];
        ushort2 o;
        o.x = f2bf(v.x);
        o.y = f2bf(v.y);
        ((ushort2*)sW)[k] = o;
    }
    __syncthreads();
    int lane = tid & 63;
    int wv = tid >> 6;
    int l15 = lane & 15;
    int lg = lane >> 4;
    short8v bfrag[4][4];
#pragma unroll
    for (int kt = 0; kt < 4; kt++)
#pragma unroll
        for (int ct = 0; ct < 4; ct++) {
            short8v f;
#pragma unroll
            for (int e = 0; e < 8; e++)
                f[e] = (short)sW[(kt * 32 + lg * 8 + e) * NEU + ct * 16 + l15];
            bfrag[kt][ct] = f;
        }
    long long row0 = (long long)blockIdx.x * 64 + wv * 16;
    if (row0 >= N) return;
    bool rowok = (row0 + l15) < N;
    const float* xr = x + (size_t)(row0 + l15) * DIN;
    f32x4 acc[4];
#pragma unroll
    for (int ct = 0; ct < 4; ct++) acc[ct] = (f32x4){0.f, 0.f, 0.f, 0.f};
#pragma unroll
    for (int kt = 0; kt < 4; kt++) {
        short8v af = (short8v){0, 0, 0, 0, 0, 0, 0, 0};
        if (rowok) {
            float4 v0 = *((const float4*)(xr + kt * 32 + lg * 8));
            float4 v1 = *((const float4*)(xr + kt * 32 + lg * 8 + 4));
            af[0] = (short)f2bf(v0.x); af[1] = (short)f2bf(v0.y);
            af[2] = (short)f2bf(v0.z); af[3] = (short)f2bf(v0.w);
            af[4] = (short)f2bf(v1.x); af[5] = (short)f2bf(v1.y);
            af[6] = (short)f2bf(v1.z); af[7] = (short)f2bf(v1.w);
        }
#pragma unroll
        for (int ct = 0; ct < 4; ct++)
            acc[ct] = __builtin_amdgcn_mfma_f32_16x16x32_bf16(af, bfrag[kt][ct], acc[ct], 0, 0, 0);
    }
#pragma unroll
    for (int r = 0; r < 4; r++) {
        long long rr = row0 + lg * 4 + r;
        if (rr < N) {
            float dv = dinv[rr];
#pragma unroll
            for (int ct = 0; ct < 4; ct++) {
                float v = acc[ct][r];
                yb[(size_t)rr * NEU + ct * 16 + l15] = f2bf(v);
                g0[(size_t)rr * NEU + ct * 16 + l15] = f2bf(dv * v);
            }
        }
    }
}

// ---------------- fused APPNP pull step: gather+add of pre-scaled rows ------
// one 64-lane wave per dst node, 16 lanes per edge (ushort4/lane).
// 8-edge main step, 4-edge tail (pad via zero-row N). Epilogue:
// h = 0.9*dd*(acc+g[v]) + 0.1*y[v]; MODE0 stores g_out = dd*h (bf16);
// MODE1 stores relu(h+b1) (f32).

template <int MODE>
__global__ __launch_bounds__(256) void pull_kernel(
        const int* __restrict__ rowptr, const int* __restrict__ es,
        const float* __restrict__ dinv, const ushort* __restrict__ gin,
        const ushort* __restrict__ yb, const float* __restrict__ b1,
        ushort* __restrict__ gout, float* __restrict__ h2out, int N) {
    int wid = threadIdx.x >> 6;
    int lane = threadIdx.x & 63;
    int quarter = lane >> 4;
    int l16 = lane & 15;
    int node = blockIdx.x * 4 + wid;
    if (node >= N) return;
    int beg = rowptr[node], end = rowptr[node + 1];
    float dd = dinv[node];
    const ushort4* gin4 = (const ushort4*)gin;
    float4 a0 = make_float4(0.f, 0.f, 0.f, 0.f);
    float4 a1 = make_float4(0.f, 0.f, 0.f, 0.f);
    int deg = end - beg;
    for (int base = 0; base < deg; base += 64) {
        int myi = base + lane;
        int msrc = (myi < deg) ? es[beg + myi] : N;   // N = zero row
        int cnt = min(64, deg - base);
        int quads = (cnt + 3) >> 2;
        int j = 0;
        for (; j + 1 < quads; j += 2) {
            int s0 = __shfl(msrc, 4 * j + quarter);
            int s1 = __shfl(msrc, 4 * j + 4 + quarter);
            ushort4 w0 = gin4[(uint)(s0 << 4) + l16];
            ushort4 w1 = gin4[(uint)(s1 << 4) + l16];
            a0.x += bf2f(w0.x); a0.y += bf2f(w0.y); a0.z += bf2f(w0.z); a0.w += bf2f(w0.w);
            a1.x += bf2f(w1.x); a1.y += bf2f(w1.y); a1.z += bf2f(w1.z); a1.w += bf2f(w1.w);
        }
        if (j < quads) {
            int s0 = __shfl(msrc, 4 * j + quarter);
            ushort4 w0 = gin4[(uint)(s0 << 4) + l16];
            a0.x += bf2f(w0.x); a0.y += bf2f(w0.y); a0.z += bf2f(w0.z); a0.w += bf2f(w0.w);
        }
    }
    float4 acc;
    acc.x = a0.x + a1.x;
    acc.y = a0.y + a1.y;
    acc.z = a0.z + a1.z;
    acc.w = a0.w + a1.w;
    acc.x += __shfl_xor(acc.x, 16);
    acc.y += __shfl_xor(acc.y, 16);
    acc.z += __shfl_xor(acc.z, 16);
    acc.w += __shfl_xor(acc.w, 16);
    acc.x += __shfl_xor(acc.x, 32);
    acc.y += __shfl_xor(acc.y, 32);
    acc.z += __shfl_xor(acc.z, 32);
    acc.w += __shfl_xor(acc.w, 32);
    if (quarter == 0) {
        ushort4 gv = *((const ushort4*)(gin + (size_t)node * NEU) + l16);
        ushort4 yv = *((const ushort4*)(yb + (size_t)node * NEU) + l16);
        float c9 = 0.9f * dd;
        float hx = c9 * (acc.x + bf2f(gv.x)) + 0.1f * bf2f(yv.x);
        float hy = c9 * (acc.y + bf2f(gv.y)) + 0.1f * bf2f(yv.y);
        float hz = c9 * (acc.z + bf2f(gv.z)) + 0.1f * bf2f(yv.z);
        float hw = c9 * (acc.w + bf2f(gv.w)) + 0.1f * bf2f(yv.w);
        if (MODE == 1) {
            float4 bb = *((const float4*)b1 + l16);
            float4 o;
            o.x = fmaxf(hx + bb.x, 0.f);
            o.y = fmaxf(hy + bb.y, 0.f);
            o.z = fmaxf(hz + bb.z, 0.f);
            o.w = fmaxf(hw + bb.w, 0.f);
            *((float4*)(h2out + (size_t)node * NEU) + l16) = o;
        } else {
            ushort4 o;
            o.x = f2bf(dd * hx); o.y = f2bf(dd * hy);
            o.z = f2bf(dd * hz); o.w = f2bf(dd * hw);
            *((ushort4*)(gout + (size_t)node * NEU) + l16) = o;
        }
    }
}

// ---------------- fused head: logits -> segment softmax -> weighted max-pool
// -> MLP(64->16->1). One block per graph; batch is sorted so the graph's
// nodes are a contiguous range found by binary search. Online max/sum
// softmax (pass 1 over cf); pool pass recomputes the logit (pass 2).

__global__ __launch_bounds__(256) void head_kernel(
        const int* __restrict__ batch, const float* __restrict__ cf,
        const float* __restrict__ cw, const float* __restrict__ cb,
        const float* __restrict__ h2, const float* __restrict__ aw1,
        const float* __restrict__ ab1, const float* __restrict__ aw2,
        const float* __restrict__ ab2, float* __restrict__ out, int N) {
    int g = blockIdx.x;
    int tid = threadIdx.x;
    __shared__ int sbound[2];
    __shared__ float redm[256];
    __shared__ float redz[256];
    __shared__ float pooled[64];
    __shared__ float sa[16];
    if (tid < 2) {
        int target = g + tid;
        int lo = 0, hi = N;
        while (lo < hi) {
            int mid = (lo + hi) >> 1;
            if (batch[mid] < target) lo = mid + 1; else hi = mid;
        }
        sbound[tid] = lo;
    }
    __syncthreads();
    int s0 = sbound[0], e0 = sbound[1];
    float w0 = cw[0], w1 = cw[1], w2 = cw[2], w3 = cw[3];
    float w4 = cw[4], w5 = cw[5], w6 = cw[6], w7 = cw[7];
    float cb0 = cb[0];
    // pass 1: online max + sum of exp
    float m = -INFINITY, z = 0.f;
    for (int i = s0 + tid; i < e0; i += 256) {
        const float4* c = (const float4*)(cf + (size_t)i * 8);
        float4 A = c[0], B = c[1];
        float l = A.x * w0 + A.y * w1 + A.z * w2 + A.w * w3
                + B.x * w4 + B.y * w5 + B.z * w6 + B.w * w7 + cb0;
        float mn = fmaxf(m, l);
        z = z * __expf(m - mn) + __expf(l - mn);
        m = mn;
    }
    redm[tid] = m; redz[tid] = z;
    __syncthreads();
    for (int w = 128; w > 0; w >>= 1) {
        if (tid < w) {
            float ma = redm[tid], mb = redm[tid + w];
            float za = redz[tid], zb = redz[tid + w];
            float mn = fmaxf(ma, mb);
            redz[tid] = (mn == -INFINITY) ? 0.f
                       : za * __expf(ma - mn) + zb * __expf(mb - mn);
            redm[tid] = mn;
        }
        __syncthreads();
    }
    float M = redm[0];
    float scale = (float)(e0 - s0) / redz[0];
    __syncthreads();
    // pass 2: weighted segment max-pool (recompute logit per row)
    int j = tid & 63, r = tid >> 6;
    float mx = -INFINITY;
    for (int i = s0 + r; i < e0; i += 4) {
        const float4* c = (const float4*)(cf + (size_t)i * 8);
        float4 A = c[0], B = c[1];
        float l = A.x * w0 + A.y * w1 + A.z * w2 + A.w * w3
                + B.x * w4 + B.y * w5 + B.z * w6 + B.w * w7 + cb0;
        float p = __expf(l - M) * scale;
        mx = fmaxf(mx, p * h2[(size_t)i * NEU + j]);
    }
    redm[tid] = mx;
    __syncthreads();
    if (r == 0)
        pooled[j] = fmaxf(fmaxf(redm[j], redm[64 + j]),
                          fmaxf(redm[128 + j], redm[192 + j]));
    __syncthreads();
    if (tid < 16) {
        float acc = ab1[tid];
#pragma unroll
        for (int k = 0; k < 64; k++) acc = fmaf(pooled[k], aw1[k * 16 + tid], acc);
        sa[tid] = fmaxf(acc, 0.f);
    }
    __syncthreads();
    if (tid == 0) {
        float o = ab2[0];
#pragma unroll
        for (int k = 0; k < 16; k++) o = fmaf(sa[k], aw2[k], o);
        out[g] = o;
    }
}

// ---------------------------------------------------------------------------

extern "C" void kernel_launch(void* const* d_in, const int* in_sizes, int n_in,
                              void* d_out, int out_size, void* d_ws, size_t ws_size,
                              hipStream_t stream) {
    const float* x       = (const float*)d_in[0];
    const float* cf      = (const float*)d_in[1];
    const int*   ei      = (const int*)d_in[2];
    const int*   batch   = (const int*)d_in[3];
    const float* nn1_w   = (const float*)d_in[5];
    const float* nn1_b   = (const float*)d_in[6];
    const float* close_w = (const float*)d_in[7];
    const float* close_b = (const float*)d_in[8];
    const float* att1_w  = (const float*)d_in[9];
    const float* att1_b  = (const float*)d_in[10];
    const float* att2_w  = (const float*)d_in[11];
    const float* att2_b  = (const float*)d_in[12];
    float* out = (float*)d_out;

    int N = in_sizes[0] / DIN;
    int E = in_sizes[2] / 2;
    int G = out_size;

    const int* src = ei;
    const int* dst = ei + E;

    char* w = (char*)d_ws;
    size_t off = 0;
    auto alloc = [&](size_t bytes) -> void* {
        void* ptr = w + off;
        off += (bytes + 511) & ~(size_t)511;
        return ptr;
    };
    int NB = (N + BK2 - 1) >> BKSHIFT2;   // 196 for N=100K (<= MAXNB)

    ushort* yb     = (ushort*)alloc((size_t)N * NEU * 2);          // x @ W1
    ushort* g0     = (ushort*)alloc(((size_t)N + 1) * NEU * 2);    // dinv*h bufs (+pad row)
    ushort* g1     = (ushort*)alloc(((size_t)N + 1) * NEU * 2);
    ushort* g2     = (ushort*)alloc(((size_t)N + 1) * NEU * 2);
    float* h2      = (float*)alloc((size_t)N * NEU * 4);           // relu(prop+b1), f32
    float* dinv    = (float*)alloc((size_t)N * 4);
    int*   rowptr  = (int*)alloc(((size_t)N + 1) * 4);
    int*   es      = (int*)alloc((size_t)E * 4);
    int*   bcur    = (int*)alloc((size_t)NB * 4);
    int*   bbase   = (int*)alloc(((size_t)NB + 1) * 4);
    int*   pk      = (int*)alloc((size_t)NB * BKCAP * 4);
    (void)ws_size; (void)n_in;

    hipMemsetAsync(bcur, 0, (size_t)NB * 4, stream);

    // --- CSR build: bin -> scan -> per-bucket LDS counting sort (makes dinv) ---
    binA_kernel<<<256, 256, 0, stream>>>(src, dst, bcur, pk, E, NB);
    bscan_kernel<<<1, 256, 0, stream>>>(bcur, bbase, NB);
    binB_kernel<<<NB, 256, 0, stream>>>(bcur, bbase, pk, es, rowptr, dinv, N, NB);

    // --- y = x @ W1 via MFMA; also g0 = dinv*y and pad-row zeroing ---
    fc1_kernel<<<(N + 63) / 64, 256, 0, stream>>>(x, nn1_w, dinv, yb, g0, g1, g2, N);

    // --- APPNP: 3 pulls on pre-scaled rows; last applies b1+relu ---
    pull_kernel<0><<<(N + 3) / 4, 256, 0, stream>>>(rowptr, es, dinv, g0, yb, nn1_b, g1, nullptr, N);
    pull_kernel<0><<<(N + 3) / 4, 256, 0, stream>>>(rowptr, es, dinv, g1, yb, nn1_b, g2, nullptr, N);
    pull_kernel<1><<<(N + 3) / 4, 256, 0, stream>>>(rowptr, es, dinv, g2, yb, nn1_b, nullptr, h2, N);

    // --- fused head: logits -> segment softmax -> pool -> MLP ---
    head_kernel<<<G, 256, 0, stream>>>(batch, cf, close_w, close_b, h2,
                                       att1_w, att1_b, att2_w, att2_b, out, N);
}

// Round 12
// 238.436 us; speedup vs baseline: 1.0180x; 1.0180x over previous
//
#include <hip/hip_runtime.h>
#include <cstdint>
#include <cstddef>

// ---------------------------------------------------------------------------
// APPNPNet_Structural: FC1-first (prop commutes with right-mul) -> APPNP K=3
// in 64-dim bf16 pre-scaled space -> fused head (softmax pool + MLP).
// Round 12: binA rebuilt as block-local LDS counting sort (kills scattered
// 4B append writes, the suspected hidden ~40us); bscan merged into binB;
// pull with 4-deep unroll at 4-edge granularity. 8 dispatches.
// ---------------------------------------------------------------------------

#define DIN 128
#define NEU 64
#define BK2 512            // nodes per bucket
#define BKSHIFT2 9
#define BKCAP 16384        // per-bucket global staging capacity (mean 8192)
#define ESCAP 12288        // per-bucket LDS sort capacity (48KB)
#define MAXNB 256
#define ASTAGE 6400        // binA per-block LDS stage (chunk = 6250 max)

typedef __attribute__((ext_vector_type(8))) short short8v;   // 8 bf16 (4 VGPRs)
typedef __attribute__((ext_vector_type(4))) float f32x4;     // 4 fp32 acc

// bf16 helpers: storage = ushort, math = f32.
__device__ inline float bf2f(unsigned short h) {
    return __uint_as_float(((unsigned)h) << 16);
}
__device__ inline unsigned short f2bf(float f) {   // round-to-nearest-even
    unsigned u = __float_as_uint(f);
    unsigned r = u + 0x7FFFu + ((u >> 16) & 1u);
    return (unsigned short)(r >> 16);
}

// ---------------- Phase A: coarse binning via LDS counting sort ----------------
// Per block: histogram its edge chunk over NB buckets, LDS-scan, reserve global
// ranges, scatter packed edges into LDS stage (recording global index), then
// stream out. All global writes are coalesced bucket-runs (~128B each).

__global__ __launch_bounds__(256) void binA_kernel(
        const int* __restrict__ src, const int* __restrict__ dst,
        int* __restrict__ bcur, int* __restrict__ pk, int E, int NB) {
    __shared__ int hist[MAXNB];
    __shared__ int lstart[MAXNB];
    __shared__ int lcur[MAXNB];
    __shared__ int resv[MAXNB];
    __shared__ int sh[256];
    __shared__ int stage[ASTAGE];
    __shared__ int gidx[ASTAGE];
    int nchunk = gridDim.x;
    int chunk = (E + nchunk - 1) / nchunk;
    int lo = blockIdx.x * chunk;
    int hi = min(E, lo + chunk);
    int t = threadIdx.x;
    for (int b = t; b < NB; b += 256) hist[b] = 0;
    __syncthreads();
    for (int i = lo + t; i < hi; i += 256)
        atomicAdd(&hist[dst[i] >> BKSHIFT2], 1);
    __syncthreads();
    int c = (t < NB) ? hist[t] : 0;
    sh[t] = c;
    __syncthreads();
    for (int d = 1; d < 256; d <<= 1) {
        int u = (t >= d) ? sh[t - d] : 0;
        __syncthreads();
        sh[t] += u;
        __syncthreads();
    }
    if (t < NB) {
        int excl = sh[t] - c;
        lstart[t] = excl;
        lcur[t] = excl;
        resv[t] = atomicAdd(&bcur[t], c);
    }
    __syncthreads();
    for (int i = lo + t; i < hi; i += 256) {
        int d = dst[i], b = d >> BKSHIFT2;
        int p = atomicAdd(&lcur[b], 1);
        stage[p] = (src[i] << BKSHIFT2) | (d & (BK2 - 1));
        gidx[p] = resv[b] + (p - lstart[b]) + b * BKCAP;
    }
    __syncthreads();
    int total = hi - lo;
    for (int q = t; q < total; q += 256)
        pk[gidx[q]] = stage[q];
}

// ---------------- Phase B: per-bucket LDS counting sort (self-scans bcur) ----

__global__ __launch_bounds__(256) void binB_kernel(
        const int* __restrict__ bcur, const int* __restrict__ pk,
        int* __restrict__ es, int* __restrict__ rowptr,
        float* __restrict__ dinv, int N, int NB) {
    __shared__ int cur[BK2];      // 2 KB: counts -> cursors
    __shared__ int sh[256];       // 1 KB: scan workspace
    __shared__ int esl[ESCAP];    // 48 KB: sorted srcs
    __shared__ int sbase[2];      // [0]=base, [1]=count
    int b = blockIdx.x;
    int t = threadIdx.x;
    int node0 = b << BKSHIFT2;
    // self-scan of bcur to get this bucket's global base
    int v = (t < NB) ? bcur[t] : 0;
    sh[t] = v;
    __syncthreads();
    for (int d = 1; d < 256; d <<= 1) {
        int u = (t >= d) ? sh[t - d] : 0;
        __syncthreads();
        sh[t] += u;
        __syncthreads();
    }
    if (t == b) { sbase[0] = sh[t] - v; sbase[1] = v; }
    __syncthreads();
    int base = sbase[0];
    int count = sbase[1];
    const int* pb = pk + (size_t)b * BKCAP;

    for (int q = t; q < BK2; q += 256) cur[q] = 0;
    __syncthreads();
    for (int i = t; i < count; i += 256)
        atomicAdd(&cur[pb[i] & (BK2 - 1)], 1);
    __syncthreads();
    int c0 = cur[2 * t], c1 = cur[2 * t + 1];
    int s = c0 + c1;
    __syncthreads();
    sh[t] = s;
    __syncthreads();
    for (int d = 1; d < 256; d <<= 1) {
        int u = (t >= d) ? sh[t - d] : 0;
        __syncthreads();
        sh[t] += u;
        __syncthreads();
    }
    int excl = sh[t] - s;
    int n0 = node0 + 2 * t;
    if (n0 < N) {
        rowptr[n0 + 1] = base + excl + c0;
        dinv[n0] = rsqrtf((float)c0 + 1.0f);
    }
    if (n0 + 1 < N) {
        rowptr[n0 + 2] = base + excl + c0 + c1;
        dinv[n0 + 1] = rsqrtf((float)c1 + 1.0f);
    }
    if (b == 0 && t == 0) rowptr[0] = 0;
    __syncthreads();
    cur[2 * t] = excl;
    cur[2 * t + 1] = excl + c0;
    __syncthreads();
    for (int i = t; i < count; i += 256) {
        int w = pb[i];
        int pos = atomicAdd(&cur[w & (BK2 - 1)], 1);
        if (pos < ESCAP) esl[pos] = w >> BKSHIFT2;
    }
    __syncthreads();
    for (int i = t; i < count; i += 256) es[base + i] = esl[i];
}

// ---------------- FC1 via MFMA: y = x @ W1, g0 = dinv*y (bf16) ----------------

__global__ __launch_bounds__(256) void fc1_kernel(
        const float* __restrict__ x, const float* __restrict__ W,
        const float* __restrict__ dinv, ushort* __restrict__ yb,
        ushort* __restrict__ g0, ushort* __restrict__ g1,
        ushort* __restrict__ g2, int N) {
    int tid = threadIdx.x;
    // zero pad-row N of all three g buffers (block 0 never early-returns)
    if (blockIdx.x == 0 && tid < 48) {
        int buf = tid >> 4, e = tid & 15;
        ushort* gp = (buf == 0) ? g0 : (buf == 1) ? g1 : g2;
        ((ushort4*)(gp + (size_t)N * NEU))[e] = make_ushort4(0, 0, 0, 0);
    }
    __shared__ ushort sW[DIN * NEU];   // bf16 W, 16 KB
    for (int k = tid; k < DIN * NEU / 2; k += 256) {
        float2 v = ((const float2*)W)[k];
        ushort2 o;
        o.x = f2bf(v.x);
        o.y = f2bf(v.y);
        ((ushort2*)sW)[k] = o;
    }
    __syncthreads();
    int lane = tid & 63;
    int wv = tid >> 6;
    int l15 = lane & 15;
    int lg = lane >> 4;
    short8v bfrag[4][4];
#pragma unroll
    for (int kt = 0; kt < 4; kt++)
#pragma unroll
        for (int ct = 0; ct < 4; ct++) {
            short8v f;
#pragma unroll
            for (int e = 0; e < 8; e++)
                f[e] = (short)sW[(kt * 32 + lg * 8 + e) * NEU + ct * 16 + l15];
            bfrag[kt][ct] = f;
        }
    long long row0 = (long long)blockIdx.x * 64 + wv * 16;
    if (row0 >= N) return;
    bool rowok = (row0 + l15) < N;
    const float* xr = x + (size_t)(row0 + l15) * DIN;
    f32x4 acc[4];
#pragma unroll
    for (int ct = 0; ct < 4; ct++) acc[ct] = (f32x4){0.f, 0.f, 0.f, 0.f};
#pragma unroll
    for (int kt = 0; kt < 4; kt++) {
        short8v af = (short8v){0, 0, 0, 0, 0, 0, 0, 0};
        if (rowok) {
            float4 v0 = *((const float4*)(xr + kt * 32 + lg * 8));
            float4 v1 = *((const float4*)(xr + kt * 32 + lg * 8 + 4));
            af[0] = (short)f2bf(v0.x); af[1] = (short)f2bf(v0.y);
            af[2] = (short)f2bf(v0.z); af[3] = (short)f2bf(v0.w);
            af[4] = (short)f2bf(v1.x); af[5] = (short)f2bf(v1.y);
            af[6] = (short)f2bf(v1.z); af[7] = (short)f2bf(v1.w);
        }
#pragma unroll
        for (int ct = 0; ct < 4; ct++)
            acc[ct] = __builtin_amdgcn_mfma_f32_16x16x32_bf16(af, bfrag[kt][ct], acc[ct], 0, 0, 0);
    }
#pragma unroll
    for (int r = 0; r < 4; r++) {
        long long rr = row0 + lg * 4 + r;
        if (rr < N) {
            float dv = dinv[rr];
#pragma unroll
            for (int ct = 0; ct < 4; ct++) {
                float v = acc[ct][r];
                yb[(size_t)rr * NEU + ct * 16 + l15] = f2bf(v);
                g0[(size_t)rr * NEU + ct * 16 + l15] = f2bf(dv * v);
            }
        }
    }
}

// ---------------- fused APPNP pull step: gather+add of pre-scaled rows ------
// one 64-lane wave per dst node, 16 lanes per edge (ushort4/lane).
// 4-deep unrolled main loop at 4-edge granularity, 1-edge tail iterations.
// Pad lanes gather zero-row N. Epilogue: h = 0.9*dd*(acc+g[v]) + 0.1*y[v];
// MODE0 stores g_out = dd*h (bf16); MODE1 stores relu(h+b1) (f32).

__device__ inline void acc4(float4& a, ushort4 w) {
    a.x += bf2f(w.x); a.y += bf2f(w.y); a.z += bf2f(w.z); a.w += bf2f(w.w);
}

template <int MODE>
__global__ __launch_bounds__(256) void pull_kernel(
        const int* __restrict__ rowptr, const int* __restrict__ es,
        const float* __restrict__ dinv, const ushort* __restrict__ gin,
        const ushort* __restrict__ yb, const float* __restrict__ b1,
        ushort* __restrict__ gout, float* __restrict__ h2out, int N) {
    int wid = threadIdx.x >> 6;
    int lane = threadIdx.x & 63;
    int quarter = lane >> 4;
    int l16 = lane & 15;
    int node = blockIdx.x * 4 + wid;
    if (node >= N) return;
    int beg = rowptr[node], end = rowptr[node + 1];
    float dd = dinv[node];
    const ushort4* gin4 = (const ushort4*)gin;
    float4 a0 = make_float4(0.f, 0.f, 0.f, 0.f);
    float4 a1 = make_float4(0.f, 0.f, 0.f, 0.f);
    float4 a2 = make_float4(0.f, 0.f, 0.f, 0.f);
    float4 a3 = make_float4(0.f, 0.f, 0.f, 0.f);
    int deg = end - beg;
    for (int base = 0; base < deg; base += 64) {
        int myi = base + lane;
        int msrc = (myi < deg) ? es[beg + myi] : N;   // N = zero row
        int cnt = min(64, deg - base);
        int quads = (cnt + 3) >> 2;
        int j = 0;
        for (; j + 3 < quads; j += 4) {
            int s0 = __shfl(msrc, 4 * j + quarter);
            int s1 = __shfl(msrc, 4 * j + 4 + quarter);
            int s2 = __shfl(msrc, 4 * j + 8 + quarter);
            int s3 = __shfl(msrc, 4 * j + 12 + quarter);
            ushort4 w0 = gin4[(uint)(s0 << 4) + l16];
            ushort4 w1 = gin4[(uint)(s1 << 4) + l16];
            ushort4 w2 = gin4[(uint)(s2 << 4) + l16];
            ushort4 w3 = gin4[(uint)(s3 << 4) + l16];
            acc4(a0, w0); acc4(a1, w1); acc4(a2, w2); acc4(a3, w3);
        }
        for (; j < quads; j++) {
            int s0 = __shfl(msrc, 4 * j + quarter);
            ushort4 w0 = gin4[(uint)(s0 << 4) + l16];
            acc4(a0, w0);
        }
    }
    float4 acc;
    acc.x = (a0.x + a1.x) + (a2.x + a3.x);
    acc.y = (a0.y + a1.y) + (a2.y + a3.y);
    acc.z = (a0.z + a1.z) + (a2.z + a3.z);
    acc.w = (a0.w + a1.w) + (a2.w + a3.w);
    acc.x += __shfl_xor(acc.x, 16);
    acc.y += __shfl_xor(acc.y, 16);
    acc.z += __shfl_xor(acc.z, 16);
    acc.w += __shfl_xor(acc.w, 16);
    acc.x += __shfl_xor(acc.x, 32);
    acc.y += __shfl_xor(acc.y, 32);
    acc.z += __shfl_xor(acc.z, 32);
    acc.w += __shfl_xor(acc.w, 32);
    if (quarter == 0) {
        ushort4 gv = *((const ushort4*)(gin + (size_t)node * NEU) + l16);
        ushort4 yv = *((const ushort4*)(yb + (size_t)node * NEU) + l16);
        float c9 = 0.9f * dd;
        float hx = c9 * (acc.x + bf2f(gv.x)) + 0.1f * bf2f(yv.x);
        float hy = c9 * (acc.y + bf2f(gv.y)) + 0.1f * bf2f(yv.y);
        float hz = c9 * (acc.z + bf2f(gv.z)) + 0.1f * bf2f(yv.z);
        float hw = c9 * (acc.w + bf2f(gv.w)) + 0.1f * bf2f(yv.w);
        if (MODE == 1) {
            float4 bb = *((const float4*)b1 + l16);
            float4 o;
            o.x = fmaxf(hx + bb.x, 0.f);
            o.y = fmaxf(hy + bb.y, 0.f);
            o.z = fmaxf(hz + bb.z, 0.f);
            o.w = fmaxf(hw + bb.w, 0.f);
            *((float4*)(h2out + (size_t)node * NEU) + l16) = o;
        } else {
            ushort4 o;
            o.x = f2bf(dd * hx); o.y = f2bf(dd * hy);
            o.z = f2bf(dd * hz); o.w = f2bf(dd * hw);
            *((ushort4*)(gout + (size_t)node * NEU) + l16) = o;
        }
    }
}

// ---------------- fused head: logits -> segment softmax -> weighted max-pool
// -> MLP(64->16->1). One block per graph (batch sorted, binary search bounds).

__global__ __launch_bounds__(256) void head_kernel(
        const int* __restrict__ batch, const float* __restrict__ cf,
        const float* __restrict__ cw, const float* __restrict__ cb,
        const float* __restrict__ h2, const float* __restrict__ aw1,
        const float* __restrict__ ab1, const float* __restrict__ aw2,
        const float* __restrict__ ab2, float* __restrict__ out, int N) {
    int g = blockIdx.x;
    int tid = threadIdx.x;
    __shared__ int sbound[2];
    __shared__ float redm[256];
    __shared__ float redz[256];
    __shared__ float pooled[64];
    __shared__ float sa[16];
    if (tid < 2) {
        int target = g + tid;
        int lo = 0, hi = N;
        while (lo < hi) {
            int mid = (lo + hi) >> 1;
            if (batch[mid] < target) lo = mid + 1; else hi = mid;
        }
        sbound[tid] = lo;
    }
    __syncthreads();
    int s0 = sbound[0], e0 = sbound[1];
    float w0 = cw[0], w1 = cw[1], w2 = cw[2], w3 = cw[3];
    float w4 = cw[4], w5 = cw[5], w6 = cw[6], w7 = cw[7];
    float cb0 = cb[0];
    // pass 1: online max + sum of exp
    float m = -INFINITY, z = 0.f;
    for (int i = s0 + tid; i < e0; i += 256) {
        const float4* c = (const float4*)(cf + (size_t)i * 8);
        float4 A = c[0], B = c[1];
        float l = A.x * w0 + A.y * w1 + A.z * w2 + A.w * w3
                + B.x * w4 + B.y * w5 + B.z * w6 + B.w * w7 + cb0;
        float mn = fmaxf(m, l);
        z = z * __expf(m - mn) + __expf(l - mn);
        m = mn;
    }
    redm[tid] = m; redz[tid] = z;
    __syncthreads();
    for (int w = 128; w > 0; w >>= 1) {
        if (tid < w) {
            float ma = redm[tid], mb = redm[tid + w];
            float za = redz[tid], zb = redz[tid + w];
            float mn = fmaxf(ma, mb);
            redz[tid] = (mn == -INFINITY) ? 0.f
                       : za * __expf(ma - mn) + zb * __expf(mb - mn);
            redm[tid] = mn;
        }
        __syncthreads();
    }
    float M = redm[0];
    float scale = (float)(e0 - s0) / redz[0];
    __syncthreads();
    // pass 2: weighted segment max-pool (recompute logit per row)
    int j = tid & 63, r = tid >> 6;
    float mx = -INFINITY;
    for (int i = s0 + r; i < e0; i += 4) {
        const float4* c = (const float4*)(cf + (size_t)i * 8);
        float4 A = c[0], B = c[1];
        float l = A.x * w0 + A.y * w1 + A.z * w2 + A.w * w3
                + B.x * w4 + B.y * w5 + B.z * w6 + B.w * w7 + cb0;
        float p = __expf(l - M) * scale;
        mx = fmaxf(mx, p * h2[(size_t)i * NEU + j]);
    }
    redm[tid] = mx;
    __syncthreads();
    if (r == 0)
        pooled[j] = fmaxf(fmaxf(redm[j], redm[64 + j]),
                          fmaxf(redm[128 + j], redm[192 + j]));
    __syncthreads();
    if (tid < 16) {
        float acc = ab1[tid];
#pragma unroll
        for (int k = 0; k < 64; k++) acc = fmaf(pooled[k], aw1[k * 16 + tid], acc);
        sa[tid] = fmaxf(acc, 0.f);
    }
    __syncthreads();
    if (tid == 0) {
        float o = ab2[0];
#pragma unroll
        for (int k = 0; k < 16; k++) o = fmaf(sa[k], aw2[k], o);
        out[g] = o;
    }
}

// ---------------------------------------------------------------------------

extern "C" void kernel_launch(void* const* d_in, const int* in_sizes, int n_in,
                              void* d_out, int out_size, void* d_ws, size_t ws_size,
                              hipStream_t stream) {
    const float* x       = (const float*)d_in[0];
    const float* cf      = (const float*)d_in[1];
    const int*   ei      = (const int*)d_in[2];
    const int*   batch   = (const int*)d_in[3];
    const float* nn1_w   = (const float*)d_in[5];
    const float* nn1_b   = (const float*)d_in[6];
    const float* close_w = (const float*)d_in[7];
    const float* close_b = (const float*)d_in[8];
    const float* att1_w  = (const float*)d_in[9];
    const float* att1_b  = (const float*)d_in[10];
    const float* att2_w  = (const float*)d_in[11];
    const float* att2_b  = (const float*)d_in[12];
    float* out = (float*)d_out;

    int N = in_sizes[0] / DIN;
    int E = in_sizes[2] / 2;
    int G = out_size;

    const int* src = ei;
    const int* dst = ei + E;

    char* w = (char*)d_ws;
    size_t off = 0;
    auto alloc = [&](size_t bytes) -> void* {
        void* ptr = w + off;
        off += (bytes + 511) & ~(size_t)511;
        return ptr;
    };
    int NB = (N + BK2 - 1) >> BKSHIFT2;   // 196 for N=100K (<= MAXNB)

    ushort* yb     = (ushort*)alloc((size_t)N * NEU * 2);          // x @ W1
    ushort* g0     = (ushort*)alloc(((size_t)N + 1) * NEU * 2);    // dinv*h bufs (+pad row)
    ushort* g1     = (ushort*)alloc(((size_t)N + 1) * NEU * 2);
    ushort* g2     = (ushort*)alloc(((size_t)N + 1) * NEU * 2);
    float* h2      = (float*)alloc((size_t)N * NEU * 4);           // relu(prop+b1), f32
    float* dinv    = (float*)alloc((size_t)N * 4);
    int*   rowptr  = (int*)alloc(((size_t)N + 1) * 4);
    int*   es      = (int*)alloc((size_t)E * 4);
    int*   bcur    = (int*)alloc((size_t)NB * 4);
    int*   pk      = (int*)alloc((size_t)NB * BKCAP * 4);
    (void)ws_size; (void)n_in;

    hipMemsetAsync(bcur, 0, (size_t)NB * 4, stream);

    // --- CSR build: LDS-sorted binning -> per-bucket LDS counting sort ---
    binA_kernel<<<256, 256, 0, stream>>>(src, dst, bcur, pk, E, NB);
    binB_kernel<<<NB, 256, 0, stream>>>(bcur, pk, es, rowptr, dinv, N, NB);

    // --- y = x @ W1 via MFMA; also g0 = dinv*y and pad-row zeroing ---
    fc1_kernel<<<(N + 63) / 64, 256, 0, stream>>>(x, nn1_w, dinv, yb, g0, g1, g2, N);

    // --- APPNP: 3 pulls on pre-scaled rows; last applies b1+relu ---
    pull_kernel<0><<<(N + 3) / 4, 256, 0, stream>>>(rowptr, es, dinv, g0, yb, nn1_b, g1, nullptr, N);
    pull_kernel<0><<<(N + 3) / 4, 256, 0, stream>>>(rowptr, es, dinv, g1, yb, nn1_b, g2, nullptr, N);
    pull_kernel<1><<<(N + 3) / 4, 256, 0, stream>>>(rowptr, es, dinv, g2, yb, nn1_b, nullptr, h2, N);

    // --- fused head: logits -> segment softmax -> pool -> MLP ---
    head_kernel<<<G, 256, 0, stream>>>(batch, cf, close_w, close_b, h2,
                                       att1_w, att1_b, att2_w, att2_b, out, N);
}